// Round 3
// baseline (1294.930 us; speedup 1.0000x reference)
//
#include <hip/hip_runtime.h>
#include <stdint.h>

typedef unsigned short u16;
typedef unsigned int u32;
typedef __attribute__((ext_vector_type(8))) short bf16x8;
typedef __attribute__((ext_vector_type(4))) float f32x4;

#define NTOK 8192
#define DDIM 1024
#define HDIM 4096
#define NEXP 8
#define KSEL 4
#define BM 256          // output tile 256x256
#define BK 32
#define SLOTCAP 35072   // 32768 assignments + per-expert pad to x256 (<=34808), rounded up
#define MAXMT (SLOTCAP / BM)   // 137

// ---------- helpers ----------
__device__ __forceinline__ u16 f2bf(float f) {
  union { float f; u32 u; } v; v.f = f;
  u32 r = v.u + 0x7fffu + ((v.u >> 16) & 1u);   // RNE
  return (u16)(r >> 16);
}

__device__ __forceinline__ void gl_lds16(const void* g, void* l) {
  // async global->LDS; LDS dest = wave-uniform base + lane*16; global src per-lane
  __builtin_amdgcn_global_load_lds(
      (__attribute__((address_space(1))) u32*)(uintptr_t)g,
      (__attribute__((address_space(3))) u32*)l, 16, 0, 0);
}

__device__ __forceinline__ float gelu_t(float x) {
  float u = 0.7978845608028654f * (x + 0.044715f * x * x * x);
  float e = __expf(2.0f * u);
  float th = 1.0f - 2.0f / (e + 1.0f);          // overflow-safe tanh
  return 0.5f * x * (1.0f + th);
}

// ---------- x -> bf16 ----------
__global__ void k_cvt_x(const float* __restrict__ x, u16* __restrict__ xb) {
  int i = blockIdx.x * blockDim.x + threadIdx.x;
  float4 v = ((const float4*)x)[i];
  uint2 p;
  p.x = (u32)f2bf(v.x) | ((u32)f2bf(v.y) << 16);
  p.y = (u32)f2bf(v.z) | ((u32)f2bf(v.w) << 16);
  ((uint2*)xb)[i] = p;
}

// ---------- weight transpose + convert: in [E][R][C] f32 -> out [E][C][R] bf16 ----------
__global__ void k_transpose_bf16(const float* __restrict__ in, u16* __restrict__ out,
                                 int R, int C) {
  __shared__ float tile[32][33];
  int e = blockIdx.z;
  const float* src = in + (size_t)e * R * C;
  u16* dst = out + (size_t)e * R * C;
  int c0 = blockIdx.x * 32, r0 = blockIdx.y * 32;
  int tx = threadIdx.x, ty = threadIdx.y;
#pragma unroll
  for (int i = 0; i < 4; i++)
    tile[ty + i * 8][tx] = src[(size_t)(r0 + ty + i * 8) * C + c0 + tx];
  __syncthreads();
#pragma unroll
  for (int i = 0; i < 4; i++)
    dst[(size_t)(c0 + ty + i * 8) * R + r0 + tx] = f2bf(tile[tx][ty + i * 8]);
}

// ---------- phase 1: per-token top-4 (no atomics) ----------
__global__ void k_topk(const float* __restrict__ x, const float* __restrict__ rw,
                       int* __restrict__ eid, float* __restrict__ tw) {
  int token = blockIdx.x * 4 + (threadIdx.x >> 6);
  int lane = threadIdx.x & 63;
  const float* xr = x + (size_t)token * DDIM;
  float p[NEXP];
#pragma unroll
  for (int e = 0; e < NEXP; e++) p[e] = 0.f;
  for (int it = 0; it < DDIM / 64; ++it) {
    int j = it * 64 + lane;
    float xj = xr[j];
    const float* r = rw + (size_t)j * NEXP;
    float4 a = *(const float4*)r;
    float4 b = *(const float4*)(r + 4);
    p[0] += xj * a.x; p[1] += xj * a.y; p[2] += xj * a.z; p[3] += xj * a.w;
    p[4] += xj * b.x; p[5] += xj * b.y; p[6] += xj * b.z; p[7] += xj * b.w;
  }
#pragma unroll
  for (int off = 32; off; off >>= 1) {
#pragma unroll
    for (int e = 0; e < NEXP; e++) p[e] += __shfl_xor(p[e], off);
  }
  unsigned used = 0;
  int idx[KSEL]; float lg[KSEL];
#pragma unroll
  for (int k = 0; k < KSEL; k++) {
    float bv = -1e30f; int bi = 0;
#pragma unroll
    for (int e = 0; e < NEXP; e++)
      if (!((used >> e) & 1) && p[e] > bv) { bv = p[e]; bi = e; }
    used |= 1u << bi; idx[k] = bi; lg[k] = bv;
  }
  float wv[KSEL]; float wsum = 0.f;
#pragma unroll
  for (int k = 0; k < KSEL; k++) { wv[k] = __expf(lg[k] - lg[0]); wsum += wv[k]; }
  float inv = 1.f / wsum;
  if (lane < KSEL) {
    eid[token * KSEL + lane] = idx[lane];
    tw[token * KSEL + lane] = wv[lane] * inv;
  }
}

// ---------- phase 2: per-expert counts -> 256-padded offsets ----------
__global__ void k_offsets(const int* __restrict__ eid, int* __restrict__ poff) {
  __shared__ int cnt[NEXP];
  if (threadIdx.x < NEXP) cnt[threadIdx.x] = 0;
  __syncthreads();
  int l0=0,l1=0,l2=0,l3=0,l4=0,l5=0,l6=0,l7=0;
  for (int i = threadIdx.x; i < NTOK * KSEL; i += 256) {
    int v = eid[i];
    l0 += (v == 0); l1 += (v == 1); l2 += (v == 2); l3 += (v == 3);
    l4 += (v == 4); l5 += (v == 5); l6 += (v == 6); l7 += (v == 7);
  }
  atomicAdd(&cnt[0], l0); atomicAdd(&cnt[1], l1);
  atomicAdd(&cnt[2], l2); atomicAdd(&cnt[3], l3);
  atomicAdd(&cnt[4], l4); atomicAdd(&cnt[5], l5);
  atomicAdd(&cnt[6], l6); atomicAdd(&cnt[7], l7);
  __syncthreads();
  if (threadIdx.x == 0) {
    int acc = 0;
#pragma unroll
    for (int e = 0; e < NEXP; e++) {
      poff[e] = acc;
      acc += ((cnt[e] + BM - 1) / BM) * BM;
    }
    poff[NEXP] = acc;
  }
}

// ---------- phase 3: deterministic scan-scatter into combined slot list ----------
__global__ void k_scatter(const int* __restrict__ eid, const float* __restrict__ tw,
                          const int* __restrict__ poff,
                          int* __restrict__ tok_cmb, float* __restrict__ w_cmb) {
  int e = blockIdx.x;
  int base = poff[e];
  __shared__ int wave_tot[16];
  __shared__ int running;
  if (threadIdx.x == 0) running = 0;
  __syncthreads();
  int lane = threadIdx.x & 63, wave = threadIdx.x >> 6;
  for (int c = 0; c < NTOK * KSEL; c += 1024) {
    int i = c + threadIdx.x;
    bool f = (eid[i] == e);
    unsigned long long m = __ballot(f);
    int wexcl = __popcll(m & ((1ull << lane) - 1ull));
    if (lane == 0) wave_tot[wave] = __popcll(m);
    __syncthreads();
    int rbase = running;
    int wbase = 0;
    for (int wv = 0; wv < wave; wv++) wbase += wave_tot[wv];
    if (f) {
      int pos = base + rbase + wbase + wexcl;
      tok_cmb[pos] = i >> 2;
      w_cmb[pos] = tw[i];
    }
    __syncthreads();
    if (threadIdx.x == 0) {
      int s = 0;
#pragma unroll
      for (int wv = 0; wv < 16; wv++) s += wave_tot[wv];
      running = rbase + s;
    }
    __syncthreads();
  }
}

// ---------- 256x256 grouped GEMM, 8 waves, BK=32, 4 LDS buffers, counted vmcnt ----------
// LDS per operand per buffer: [256 rows][32 k] bf16 = 16 KB, st_16x32 swizzled
// (linear dest via gl_lds + inverse-swizzled global source; swizzled ds_read).
// Pipeline: while computing tile T (from buf T&3), stage tile T+3 (into buf (T+3)&3).
// vmcnt(8) once per tile => everything except tiles {T+2,T+3} complete => T+1 ready.
template <int ST, int VM>
__device__ __forceinline__ void tile_body(
    int T, char* ldsA, char* ldsB,
    bf16x8 (&afr)[8], bf16x8 (&bfr)[4], f32x4 (&acc)[8][4],
    const int (&aoff)[8], const int (&boff)[4],
    const char*& aS0, const char*& aS1, const char*& bS0, const char*& bS1,
    int w1024) {
  const char* Ab = ldsA + (T & 3) * 16384;
  const char* Bb = ldsB + (T & 3) * 16384;
  char* AbS = ldsA + ((T + 3) & 3) * 16384;
  char* BbS = ldsB + ((T + 3) & 3) * 16384;
  // ---- phase 0: read A mb0-3 + all B; stage A(T+3) ----
#pragma unroll
  for (int mb = 0; mb < 4; ++mb) afr[mb] = *(const bf16x8*)(Ab + aoff[mb]);
#pragma unroll
  for (int nb = 0; nb < 4; ++nb) bfr[nb] = *(const bf16x8*)(Bb + boff[nb]);
  if (ST) { gl_lds16(aS0, AbS + w1024); gl_lds16(aS1, AbS + 8192 + w1024); }
  __builtin_amdgcn_s_barrier();
  asm volatile("s_waitcnt lgkmcnt(0)" ::: "memory");
  __builtin_amdgcn_sched_barrier(0);
  __builtin_amdgcn_s_setprio(1);
#pragma unroll
  for (int mb = 0; mb < 4; ++mb)
#pragma unroll
    for (int nb = 0; nb < 4; ++nb)
      acc[mb][nb] = __builtin_amdgcn_mfma_f32_16x16x32_bf16(afr[mb], bfr[nb], acc[mb][nb], 0, 0, 0);
  __builtin_amdgcn_s_setprio(0);
  __builtin_amdgcn_s_barrier();
  __builtin_amdgcn_sched_barrier(0);
  // ---- phase 1: read A mb4-7; stage B(T+3); counted vmcnt ----
#pragma unroll
  for (int mb = 4; mb < 8; ++mb) afr[mb] = *(const bf16x8*)(Ab + aoff[mb]);
  if (ST) {
    gl_lds16(bS0, BbS + w1024); gl_lds16(bS1, BbS + 8192 + w1024);
    aS0 += 64; aS1 += 64; bS0 += 64; bS1 += 64;
  }
  if (VM == 8) asm volatile("s_waitcnt vmcnt(8)" ::: "memory");
  else if (VM == 4) asm volatile("s_waitcnt vmcnt(4)" ::: "memory");
  else if (VM == 0) asm volatile("s_waitcnt vmcnt(0)" ::: "memory");
  __builtin_amdgcn_sched_barrier(0);
  __builtin_amdgcn_s_barrier();
  asm volatile("s_waitcnt lgkmcnt(0)" ::: "memory");
  __builtin_amdgcn_sched_barrier(0);
  __builtin_amdgcn_s_setprio(1);
#pragma unroll
  for (int mb = 4; mb < 8; ++mb)
#pragma unroll
    for (int nb = 0; nb < 4; ++nb)
      acc[mb][nb] = __builtin_amdgcn_mfma_f32_16x16x32_bf16(afr[mb], bfr[nb], acc[mb][nb], 0, 0, 0);
  __builtin_amdgcn_s_setprio(0);
  __builtin_amdgcn_s_barrier();
  __builtin_amdgcn_sched_barrier(0);
}

template <bool IS_UP>
__global__ __launch_bounds__(512, 2) void k_moe_gemm(
    const u16* __restrict__ A, const u16* __restrict__ Bbase,
    const int* __restrict__ tok_cmb, const float* __restrict__ w_cmb,
    const int* __restrict__ poff,
    u16* __restrict__ act, float* __restrict__ out, int e_fixed) {
  // bijective XCD swizzle (m204)
  int nx = gridDim.x;
  int nwg = nx * gridDim.y;
  int flat = blockIdx.y * nx + blockIdx.x;
  int q = nwg >> 3, r = nwg & 7;
  int xcd = flat & 7, sub = flat >> 3;
  int wgid = (xcd < r ? xcd * (q + 1) : r * (q + 1) + (xcd - r) * q) + sub;
  int ntile = wgid % nx;
  int mtile = wgid / nx;

  const int pbase = (e_fixed >= 0) ? poff[e_fixed] : 0;
  const int pend = (e_fixed >= 0) ? poff[e_fixed + 1] : poff[NEXP];
  const int slot0 = pbase + mtile * BM;
  if (slot0 >= pend) return;
  int e;
  if (e_fixed >= 0) {
    e = e_fixed;
  } else {
    e = 0;
#pragma unroll
    for (int i = 1; i < NEXP; i++) e += (slot0 >= poff[i]);
  }
  const int K = IS_UP ? DDIM : HDIM;
  const int NT = K / BK;                    // 32 (up) / 128 (down)
  const size_t ROWB = (size_t)K * 2;        // K-row bytes for A and B
  const u16* B = Bbase + (size_t)e * HDIM * DDIM;

  __shared__ u16 AsBuf[4 * 8192];           // 4 bufs x 16KB
  __shared__ u16 BsBuf[4 * 8192];
  char* ldsA = (char*)AsBuf;
  char* ldsB = (char*)BsBuf;

  const int t = threadIdx.x, lane = t & 63, w = t >> 6;
  const int w1024 = w << 10;
  const int wm = w >> 2, wn = w & 3;        // 2M x 4N waves
  const int fr = lane & 15, fkb = (lane >> 4) * 16;

  // ---- staging source addresses (inverse-swizzled within-row offset) ----
  // dest byte P = j*8192 + w*1024 + lane*16 -> row = j*128 + w*16 + lane/4,
  // in-row byte = (lane&3)*16 ^ ((lane>>5)&1)<<5
  const int srow0 = w * 16 + (lane >> 2);
  const int srow1 = 128 + srow0;
  const int kb = ((lane & 3) * 16) ^ (((lane >> 5) & 1) << 5);
  size_t aRow0, aRow1;
  if (IS_UP) {
    aRow0 = (size_t)tok_cmb[slot0 + srow0] * ROWB;
    aRow1 = (size_t)tok_cmb[slot0 + srow1] * ROWB;
  } else {
    aRow0 = (size_t)(mtile * BM + srow0) * ROWB;   // local act row
    aRow1 = (size_t)(mtile * BM + srow1) * ROWB;
  }
  const char* aS0 = (const char*)A + aRow0 + kb;
  const char* aS1 = (const char*)A + aRow1 + kb;
  const char* bS0 = (const char*)B + (size_t)(ntile * BM + srow0) * ROWB + kb;
  const char* bS1 = (const char*)B + (size_t)(ntile * BM + srow1) * ROWB + kb;

  // ---- ds_read fragment offsets (swizzled) ----
  int aoff[8], boff[4];
#pragma unroll
  for (int mb = 0; mb < 8; ++mb) {
    int row = wm * 128 + mb * 16 + fr;
    aoff[mb] = (row * 64 + fkb) ^ ((((row >> 3) & 1)) << 5);
  }
#pragma unroll
  for (int nb = 0; nb < 4; ++nb) {
    int row = wn * 64 + nb * 16 + fr;
    boff[nb] = (row * 64 + fkb) ^ ((((row >> 3) & 1)) << 5);
  }

  f32x4 acc[8][4];
#pragma unroll
  for (int mb = 0; mb < 8; ++mb)
#pragma unroll
    for (int nb = 0; nb < 4; ++nb) acc[mb][nb] = (f32x4){0.f, 0.f, 0.f, 0.f};
  bf16x8 afr[8], bfr[4];

  // ---- prologue: stage tiles 0,1,2; wait tile 0 ----
#pragma unroll
  for (int tt = 0; tt < 3; ++tt) {
    char* AbS = ldsA + tt * 16384;
    char* BbS = ldsB + tt * 16384;
    gl_lds16(aS0, AbS + w1024); gl_lds16(aS1, AbS + 8192 + w1024);
    gl_lds16(bS0, BbS + w1024); gl_lds16(bS1, BbS + 8192 + w1024);
    aS0 += 64; aS1 += 64; bS0 += 64; bS1 += 64;
  }
  asm volatile("s_waitcnt vmcnt(8)" ::: "memory");
  __builtin_amdgcn_sched_barrier(0);
  __builtin_amdgcn_s_barrier();

  // ---- main loop + 3 peeled tail tiles ----
  for (int T = 0; T < NT - 3; ++T)
    tile_body<1, 8>(T, ldsA, ldsB, afr, bfr, acc, aoff, boff, aS0, aS1, bS0, bS1, w1024);
  tile_body<0, 4>(NT - 3, ldsA, ldsB, afr, bfr, acc, aoff, boff, aS0, aS1, bS0, bS1, w1024);
  tile_body<0, 0>(NT - 2, ldsA, ldsB, afr, bfr, acc, aoff, boff, aS0, aS1, bS0, bS1, w1024);
  tile_body<0, -1>(NT - 1, ldsA, ldsB, afr, bfr, acc, aoff, boff, aS0, aS1, bS0, bS1, w1024);

  // ---- epilogue ----
  if (IS_UP) {
#pragma unroll
    for (int mb = 0; mb < 8; ++mb) {
#pragma unroll
      for (int jj = 0; jj < 4; ++jj) {
        int rr = mtile * BM + wm * 128 + mb * 16 + (lane >> 4) * 4 + jj;
        u16* arow = act + (size_t)rr * HDIM + (size_t)ntile * BM + wn * 64;
#pragma unroll
        for (int nb = 0; nb < 4; ++nb)
          arow[nb * 16 + fr] = f2bf(gelu_t(acc[mb][nb][jj]));
      }
    }
  } else {
#pragma unroll
    for (int mb = 0; mb < 8; ++mb) {
#pragma unroll
      for (int jj = 0; jj < 4; ++jj) {
        int rloc = wm * 128 + mb * 16 + (lane >> 4) * 4 + jj;
        int slot = slot0 + rloc;         // pad slots have w=0 -> adds 0
        int tok = tok_cmb[slot];
        float wgt = w_cmb[slot];
        float* orow = out + (size_t)tok * DDIM + (size_t)ntile * BM + wn * 64;
#pragma unroll
        for (int nb = 0; nb < 4; ++nb)
          atomicAdd(&orow[nb * 16 + fr], wgt * acc[mb][nb][jj]);
      }
    }
  }
}

// ---------- launch ----------
extern "C" void kernel_launch(void* const* d_in, const int* in_sizes, int n_in,
                              void* d_out, int out_size, void* d_ws, size_t ws_size,
                              hipStream_t stream) {
  const float* x  = (const float*)d_in[0];
  const float* rw = (const float*)d_in[1];
  const float* up = (const float*)d_in[2];
  const float* dw = (const float*)d_in[3];
  float* out = (float*)d_out;

  char* ws = (char*)d_ws;
  size_t off = 0;
  u16* xb = (u16*)(ws + off);      off += (size_t)NTOK * DDIM * 2;          // 16 MiB
  u16* upbT = (u16*)(ws + off);    off += (size_t)NEXP * HDIM * DDIM * 2;   // 64 MiB
  u16* downbT = (u16*)(ws + off);  off += (size_t)NEXP * DDIM * HDIM * 2;   // 64 MiB
  int* eid = (int*)(ws + off);     off += (size_t)NTOK * KSEL * 4;
  float* tw = (float*)(ws + off);  off += (size_t)NTOK * KSEL * 4;
  int* poff = (int*)(ws + off);    off += 64;
  int* tok_cmb = (int*)(ws + off); off += (size_t)SLOTCAP * 4;
  float* w_cmb = (float*)(ws + off); off += (size_t)SLOTCAP * 4;
  u16* act = (u16*)(ws + off);
  size_t need_big = off + (size_t)SLOTCAP * HDIM * 2;        // ~426 MB
  const bool big = (ws_size >= need_big);

  hipMemsetAsync(d_out, 0, (size_t)NTOK * DDIM * 4, stream);
  hipMemsetAsync(tok_cmb, 0, (size_t)SLOTCAP * 8, stream);   // tok_cmb + w_cmb adjacent

  k_cvt_x<<<dim3(NTOK * DDIM / 4 / 256), dim3(256), 0, stream>>>(x, xb);
  k_transpose_bf16<<<dim3(HDIM / 32, DDIM / 32, NEXP), dim3(32, 8), 0, stream>>>(up, upbT, DDIM, HDIM);
  k_transpose_bf16<<<dim3(DDIM / 32, HDIM / 32, NEXP), dim3(32, 8), 0, stream>>>(dw, downbT, HDIM, DDIM);
  k_topk<<<dim3(NTOK / 4), dim3(256), 0, stream>>>(x, rw, eid, tw);
  k_offsets<<<dim3(1), dim3(256), 0, stream>>>(eid, poff);
  k_scatter<<<dim3(NEXP), dim3(1024), 0, stream>>>(eid, tw, poff, tok_cmb, w_cmb);

  if (big) {
    k_moe_gemm<true><<<dim3(HDIM / BM, MAXMT), dim3(512), 0, stream>>>(
        xb, upbT, tok_cmb, w_cmb, poff, act, out, -1);
    k_moe_gemm<false><<<dim3(DDIM / BM, MAXMT), dim3(512), 0, stream>>>(
        act, downbT, tok_cmb, w_cmb, poff, act, out, -1);
  } else {
    for (int e = 0; e < NEXP; e++) {
      k_moe_gemm<true><<<dim3(HDIM / BM, NTOK / BM), dim3(512), 0, stream>>>(
          xb, upbT, tok_cmb, w_cmb, poff, act, out, e);
      k_moe_gemm<false><<<dim3(DDIM / BM, NTOK / BM), dim3(512), 0, stream>>>(
          act, downbT, tok_cmb, w_cmb, poff, act, out, e);
    }
  }
}